// Round 1
// baseline (759.490 us; speedup 1.0000x reference)
//
#include <hip/hip_runtime.h>

// NodeToEdge: out[e, :] = (node_src[ids[0,e], :] + off_src[e, :])
//                       * (node_tgt[ids[1,e], :] + off_tgt[e, :])
// E = 300000, F = 256, fp32. Memory-bound streaming kernel.
// 64 threads per edge row, float4 per thread (16 B/lane coalesced).

#define FEAT 256

__global__ __launch_bounds__(256) void node_to_edge_kernel(
    const float* __restrict__ node_src,
    const float* __restrict__ node_tgt,
    const int* __restrict__ edge_ids,   // [2, E] flat int32
    const float* __restrict__ off_src,  // [E, F]
    const float* __restrict__ off_tgt,  // [E, F]
    float* __restrict__ out,            // [E, F]
    int num_edges)
{
    const int tid = blockIdx.x * blockDim.x + threadIdx.x;
    const int e  = tid >> 6;        // 64 threads per edge row
    const int c4 = (tid & 63) << 2; // float column (4 floats per thread)
    if (e >= num_edges) return;

    const int sid = edge_ids[e];              // edge_ids[0][e]
    const int tgt = edge_ids[num_edges + e];  // edge_ids[1][e]

    const int eo = e * FEAT + c4;   // max 300000*256 = 76.8M < 2^31
    const float4 a  = *(const float4*)(node_src + sid * FEAT + c4);
    const float4 b  = *(const float4*)(node_tgt + tgt * FEAT + c4);
    const float4 oa = *(const float4*)(off_src + eo);
    const float4 ob = *(const float4*)(off_tgt + eo);

    float4 r;
    r.x = (a.x + oa.x) * (b.x + ob.x);
    r.y = (a.y + oa.y) * (b.y + ob.y);
    r.z = (a.z + oa.z) * (b.z + ob.z);
    r.w = (a.w + oa.w) * (b.w + ob.w);
    *(float4*)(out + eo) = r;
}

extern "C" void kernel_launch(void* const* d_in, const int* in_sizes, int n_in,
                              void* d_out, int out_size, void* d_ws, size_t ws_size,
                              hipStream_t stream) {
    const float* node_src = (const float*)d_in[0];
    const float* node_tgt = (const float*)d_in[1];
    const int*   edge_ids = (const int*)d_in[2];
    const float* off_src  = (const float*)d_in[3];
    const float* off_tgt  = (const float*)d_in[4];
    float* out = (float*)d_out;

    const int num_edges = in_sizes[3] / FEAT;  // off_edge_src is [E, F]
    const long long total_threads = (long long)num_edges * 64;
    const int block = 256;
    const int grid = (int)((total_threads + block - 1) / block);

    node_to_edge_kernel<<<grid, block, 0, stream>>>(
        node_src, node_tgt, edge_ids, off_src, off_tgt, out, num_edges);
}